// Round 1
// 309.434 us; speedup vs baseline: 1.0163x; 1.0163x over previous
//
#include <hip/hip_runtime.h>
#include <hip/hip_bf16.h>

// Problem constants
#define DIMD   1024
#define BATCH  4
#define SEQ    4096
#define NTOK   (BATCH * SEQ)   // 16384
#define CHUNK  64              // recurrence chunk length
#define NCHUNK (SEQ / CHUNK)   // 64

// K-tiling for both MFMA GEMMs: 64-deep K tiles, 16 tiles total.
#define KBK    64
#define NKT    (DIMD / KBK)

typedef unsigned short ushort_t;
typedef __attribute__((ext_vector_type(8))) __bf16   bf16x8;
typedef __attribute__((ext_vector_type(4))) float    f32x4;
typedef __attribute__((ext_vector_type(8))) ushort_t u16x8;

__device__ __forceinline__ float b2f(ushort_t u) {
    union { unsigned int i; float f; } x;
    x.i = ((unsigned int)u) << 16;
    return x.f;
}

__device__ __forceinline__ ushort_t f2b(float f) {
    union { float f; unsigned int i; } x;
    x.f = f;
    unsigned int r = x.i + 0x7fffu + ((x.i >> 16) & 1u);  // RNE
    return (ushort_t)(r >> 16);
}

// 16B global->LDS direct copy. LDS dest must be wave-uniform-base + lane*16
// (linear); swizzling is done on the per-lane GLOBAL source address.
#define GLL(gsrc, ldst) __builtin_amdgcn_global_load_lds( \
    (__attribute__((address_space(1))) void*)(gsrc), \
    (__attribute__((address_space(3))) void*)(ldst), 16, 0, 0)

// ---------------------------------------------------------------------------
// f32 -> bf16, 8 elem/thread, 16B stores.
// ---------------------------------------------------------------------------
__global__ __launch_bounds__(256)
void conv_f2b(const float* __restrict__ src, ushort_t* __restrict__ dst, int n8)
{
    const int i = blockIdx.x * 256 + threadIdx.x;
    if (i >= n8) return;
    const float4* s4 = (const float4*)src;
    const float4 a = s4[i * 2];
    const float4 b = s4[i * 2 + 1];
    u16x8 o;
    o[0] = f2b(a.x); o[1] = f2b(a.y); o[2] = f2b(a.z); o[3] = f2b(a.w);
    o[4] = f2b(b.x); o[5] = f2b(b.y); o[6] = f2b(b.z); o[7] = f2b(b.w);
    *(u16x8*)(dst + (size_t)i * 8) = o;
}

// All 4 weight matrices in one launch; blockIdx.y selects the matrix.
__global__ __launch_bounds__(256)
void conv_w(const float* __restrict__ W0, const float* __restrict__ W1,
            const float* __restrict__ W2, const float* __restrict__ W3,
            ushort_t* __restrict__ dst)
{
    const int m = blockIdx.y;
    const float* src = (m == 0) ? W0 : (m == 1) ? W1 : (m == 2) ? W2 : W3;
    const int i = blockIdx.x * 256 + threadIdx.x;
    const float4* s4 = (const float4*)src;
    const float4 a = s4[i * 2];
    const float4 b = s4[i * 2 + 1];
    u16x8 o;
    o[0] = f2b(a.x); o[1] = f2b(a.y); o[2] = f2b(a.z); o[3] = f2b(a.w);
    o[4] = f2b(b.x); o[5] = f2b(b.y); o[6] = f2b(b.z); o[7] = f2b(b.w);
    *(u16x8*)(dst + (size_t)m * DIMD * DIMD + (size_t)i * 8) = o;
}

// ---------------------------------------------------------------------------
// Fused 3-projection GEMM, 4-phase counted-vmcnt pipeline.
// Block 256x64, 512 threads (8 waves: 4 row-chunks x 2 col-halves).
// LDS: A 2x32KB + 3x B 2x8KB = 112 KB, 1 block/CU.
// XOR swizzle: k-chunk ^= (row&7) on global source + LDS read (involution).
// Prefetch: B(kt+1) issued at P0, A(kt+2) issued at P2 (buffer vacated after
// P1's lgkmcnt(0) + barrier). Boundary: s_waitcnt vmcnt(4) keeps A(kt+2)
// in flight across the barrier; never drains to 0 mid-loop.
// Numerics: identical k-accumulation order as the previous kernel.
// ---------------------------------------------------------------------------
__global__ __launch_bounds__(512, 2)
void gemm_kvr(const ushort_t* __restrict__ A,
              const ushort_t* __restrict__ Wk,
              const ushort_t* __restrict__ Wv,
              const ushort_t* __restrict__ Wr,
              const float* __restrict__ td,
              ushort_t* __restrict__ Okv,
              ushort_t* __restrict__ Or,
              float* __restrict__ cs)
{
    __shared__ __align__(16) ushort_t As[2][256 * KBK];  // 2 x 32 KB
    __shared__ __align__(16) ushort_t Bk[2][64 * KBK];   // 2 x 8 KB
    __shared__ __align__(16) ushort_t Bv[2][64 * KBK];
    __shared__ __align__(16) ushort_t Br[2][64 * KBK];

    const int tid  = threadIdx.x;
    const int lane = tid & 63;
    const int wv   = tid >> 6;        // 0..7
    const int wr   = wv >> 1;         // 0..3 : 64-row chunk of the block
    const int wc   = wv & 1;          // 0..1 : 32-col half
    const int lrow = lane & 15;
    const int kq   = lane >> 4;
    const int s8   = lrow & 7;
    const int sw0  = (kq ^ s8) * 8;        // swizzled elem offset, ksub=0
    const int sw1  = ((kq + 4) ^ s8) * 8;  // swizzled elem offset, ksub=1

    const int row0 = blockIdx.x * 256;
    const int e0   = blockIdx.y * 64;

    // Staging: dest chunk (row, q) <- global (row, q ^ (row&7)).
    const int r_  = tid >> 3;                       // 0..63
    const int q_  = ((tid & 7) ^ (r_ & 7)) * 8;
    const size_t aoffs = (size_t)(row0 + r_) * DIMD + q_;
    const size_t boffs = (size_t)(e0 + r_) * DIMD + q_;

#define KVR_STAGE_A(dst, k0) do { \
    _Pragma("unroll") \
    for (int it_ = 0; it_ < 4; ++it_) \
        GLL(A + aoffs + (size_t)it_ * 64 * DIMD + (k0), \
            (char*)(dst) + (tid + it_ * 512) * 16); \
} while (0)

#define KVR_STAGE_B(dk, dv, dr, k0) do { \
    GLL(Wk + boffs + (k0), (char*)(dk) + tid * 16); \
    GLL(Wv + boffs + (k0), (char*)(dv) + tid * 16); \
    GLL(Wr + boffs + (k0), (char*)(dr) + tid * 16); \
} while (0)

    f32x4 ak[4][2], av[4][2], aR[4][2];
#pragma unroll
    for (int i = 0; i < 4; i++)
#pragma unroll
        for (int j = 0; j < 2; j++) {
            ak[i][j] = f32x4{0.f, 0.f, 0.f, 0.f};
            av[i][j] = f32x4{0.f, 0.f, 0.f, 0.f};
            aR[i][j] = f32x4{0.f, 0.f, 0.f, 0.f};
        }

    // Prologue: A0, B0, A1 in flight; wait A0+B0, keep A1 (vmcnt(4)).
    KVR_STAGE_A(&As[0][0], 0);
    KVR_STAGE_B(&Bk[0][0], &Bv[0][0], &Br[0][0], 0);
    asm volatile("" ::: "memory");                 // pin issue-group order
    KVR_STAGE_A(&As[1][0], KBK);
    asm volatile("s_waitcnt vmcnt(4)" ::: "memory");
    __builtin_amdgcn_s_barrier();

    auto tile = [&](int kt, ushort_t* Asb, ushort_t* Bkb, ushort_t* Bvb,
                    ushort_t* Brb, ushort_t* Bkn, ushort_t* Bvn, ushort_t* Brn) {
        bf16x8 af0[4], af1[4], b0[2], b1[2], c0[2], c1[2], d0[2], d1[2];

        // ---- P0: read A/ Bk/Bv (ksub0); issue B(kt+1); mfma k,v ksub0
#pragma unroll
        for (int i = 0; i < 4; i++)
            af0[i] = *(const bf16x8*)(Asb + (wr * 64 + i * 16 + lrow) * KBK + sw0);
#pragma unroll
        for (int j = 0; j < 2; j++) {
            const int bo = (wc * 32 + j * 16 + lrow) * KBK + sw0;
            b0[j] = *(const bf16x8*)(Bkb + bo);
            c0[j] = *(const bf16x8*)(Bvb + bo);
        }
        if (kt + 1 < NKT) KVR_STAGE_B(Bkn, Bvn, Brn, (kt + 1) * KBK);
        __builtin_amdgcn_s_barrier();
        asm volatile("s_waitcnt lgkmcnt(0)" ::: "memory");
        __builtin_amdgcn_sched_barrier(0);
        __builtin_amdgcn_s_setprio(1);
#pragma unroll
        for (int i = 0; i < 4; i++)
#pragma unroll
            for (int j = 0; j < 2; j++) {
                ak[i][j] = __builtin_amdgcn_mfma_f32_16x16x32_bf16(af0[i], b0[j], ak[i][j], 0, 0, 0);
                av[i][j] = __builtin_amdgcn_mfma_f32_16x16x32_bf16(af0[i], c0[j], av[i][j], 0, 0, 0);
            }
        __builtin_amdgcn_s_setprio(0);
        __builtin_amdgcn_s_barrier();

        // ---- P1: read Br (ksub0) + A (ksub1); mfma r ksub0
#pragma unroll
        for (int j = 0; j < 2; j++)
            d0[j] = *(const bf16x8*)(Brb + (wc * 32 + j * 16 + lrow) * KBK + sw0);
#pragma unroll
        for (int i = 0; i < 4; i++)
            af1[i] = *(const bf16x8*)(Asb + (wr * 64 + i * 16 + lrow) * KBK + sw1);
        __builtin_amdgcn_s_barrier();
        asm volatile("s_waitcnt lgkmcnt(0)" ::: "memory");
        __builtin_amdgcn_sched_barrier(0);
        __builtin_amdgcn_s_setprio(1);
#pragma unroll
        for (int i = 0; i < 4; i++)
#pragma unroll
            for (int j = 0; j < 2; j++)
                aR[i][j] = __builtin_amdgcn_mfma_f32_16x16x32_bf16(af0[i], d0[j], aR[i][j], 0, 0, 0);
        __builtin_amdgcn_s_setprio(0);
        __builtin_amdgcn_s_barrier();

        // ---- P2: read Bk/Bv (ksub1); issue A(kt+2) into vacated A buffer
        //      (safe: all waves drained af1 reads at P1 lgkm + P1-end barrier)
#pragma unroll
        for (int j = 0; j < 2; j++) {
            const int bo = (wc * 32 + j * 16 + lrow) * KBK + sw1;
            b1[j] = *(const bf16x8*)(Bkb + bo);
            c1[j] = *(const bf16x8*)(Bvb + bo);
        }
        if (kt + 2 < NKT) KVR_STAGE_A(Asb, (kt + 2) * KBK);
        __builtin_amdgcn_s_barrier();
        asm volatile("s_waitcnt lgkmcnt(0)" ::: "memory");
        __builtin_amdgcn_sched_barrier(0);
        __builtin_amdgcn_s_setprio(1);
#pragma unroll
        for (int i = 0; i < 4; i++)
#pragma unroll
            for (int j = 0; j < 2; j++) {
                ak[i][j] = __builtin_amdgcn_mfma_f32_16x16x32_bf16(af1[i], b1[j], ak[i][j], 0, 0, 0);
                av[i][j] = __builtin_amdgcn_mfma_f32_16x16x32_bf16(af1[i], c1[j], av[i][j], 0, 0, 0);
            }
        __builtin_amdgcn_s_setprio(0);
        __builtin_amdgcn_s_barrier();

        // ---- P3: read Br (ksub1); mfma r ksub1; counted-vmcnt boundary
#pragma unroll
        for (int j = 0; j < 2; j++)
            d1[j] = *(const bf16x8*)(Brb + (wc * 32 + j * 16 + lrow) * KBK + sw1);
        __builtin_amdgcn_s_barrier();
        asm volatile("s_waitcnt lgkmcnt(0)" ::: "memory");
        __builtin_amdgcn_sched_barrier(0);
        __builtin_amdgcn_s_setprio(1);
#pragma unroll
        for (int i = 0; i < 4; i++)
#pragma unroll
            for (int j = 0; j < 2; j++)
                aR[i][j] = __builtin_amdgcn_mfma_f32_16x16x32_bf16(af1[i], d1[j], aR[i][j], 0, 0, 0);
        __builtin_amdgcn_s_setprio(0);
        // Drain A(kt+1)+B(kt+1); keep A(kt+2) (last 4 issued) in flight.
        if (kt < NKT - 2)       asm volatile("s_waitcnt vmcnt(4)" ::: "memory");
        else if (kt == NKT - 2) asm volatile("s_waitcnt vmcnt(0)" ::: "memory");
        __builtin_amdgcn_s_barrier();
    };

    for (int m = 0; m < NKT / 2; ++m) {
        tile(2 * m,     &As[0][0], &Bk[0][0], &Bv[0][0], &Br[0][0],
                        &Bk[1][0], &Bv[1][0], &Br[1][0]);
        tile(2 * m + 1, &As[1][0], &Bk[1][0], &Bv[1][0], &Br[1][0],
                        &Bk[0][0], &Bv[0][0], &Br[0][0]);
    }

    // Epilogue 1: kv & r stores. C/D layout: col = lane&15, row = quad*4+reg.
#pragma unroll
    for (int i = 0; i < 4; i++)
#pragma unroll
        for (int j = 0; j < 2; j++)
#pragma unroll
            for (int r = 0; r < 4; r++) {
                const int row = row0 + wr * 64 + i * 16 + kq * 4 + r;
                const int col = e0 + wc * 32 + j * 16 + lrow;
                const size_t o = (size_t)row * DIMD + col;
                Okv[o] = f2b(ak[i][j][r] * av[i][j][r]);
                Or[o]  = f2b(1.f / (1.f + __expf(-aR[i][j][r])));
            }

    // Epilogue 2: per-chunk weighted sum  s(d) = sum_row decay^(63-row) k*v.
#pragma unroll
    for (int j = 0; j < 2; j++) {
        const int col = e0 + wc * 32 + j * 16 + lrow;
        const float w = -__expf(td[col]);
        float s = 0.f;
#pragma unroll
        for (int i = 0; i < 4; i++)
#pragma unroll
            for (int r = 0; r < 4; r++) {
                const int rl = i * 16 + kq * 4 + r;           // 0..63
                s += __expf(w * (float)(63 - rl)) * ak[i][j][r] * av[i][j][r];
            }
        s += __shfl_xor(s, 16);
        s += __shfl_xor(s, 32);
        if (kq == 0) {
            const int gchunk = (row0 >> 6) + wr;              // global chunk id
            cs[(size_t)gchunk * DIMD + col] = s;
        }
    }
#undef KVR_STAGE_A
#undef KVR_STAGE_B
}

// ---------------------------------------------------------------------------
// Final GEMM: C[n,e] = sum_d A[n,d] * W[e,d], f32 out.
// 256x256 block, 512 threads (2 row-halves x 4 col-quarters, wave 128x64),
// same 4-phase counted-vmcnt pipeline + swizzle. LDS 128 KB, 1 block/CU.
// Grid = 64x4 = 256 blocks -> one full round over the chip.
// ---------------------------------------------------------------------------
__global__ __launch_bounds__(512, 2)
void gemm_bt(const ushort_t* __restrict__ A,
             const ushort_t* __restrict__ W,
             float* __restrict__ Of)
{
    __shared__ __align__(16) ushort_t As[2][256 * KBK];  // 2 x 32 KB
    __shared__ __align__(16) ushort_t Bs[2][256 * KBK];  // 2 x 32 KB

    const int tid  = threadIdx.x;
    const int lane = tid & 63;
    const int wv   = tid >> 6;
    const int wr   = wv >> 2;         // 0..1 : 128-row half
    const int wc   = wv & 3;          // 0..3 : 64-col quarter
    const int lrow = lane & 15;
    const int kq   = lane >> 4;
    const int s8   = lrow & 7;
    const int sw0  = (kq ^ s8) * 8;
    const int sw1  = ((kq + 4) ^ s8) * 8;

    const int row0 = blockIdx.x * 256;
    const int e0   = blockIdx.y * 256;

    const int r_  = tid >> 3;
    const int q_  = ((tid & 7) ^ (r_ & 7)) * 8;
    const size_t aoffs = (size_t)(row0 + r_) * DIMD + q_;
    const size_t boffs = (size_t)(e0 + r_) * DIMD + q_;

#define BT_STAGE_A(dst, k0) do { \
    _Pragma("unroll") \
    for (int it_ = 0; it_ < 4; ++it_) \
        GLL(A + aoffs + (size_t)it_ * 64 * DIMD + (k0), \
            (char*)(dst) + (tid + it_ * 512) * 16); \
} while (0)

#define BT_STAGE_B(dst, k0) do { \
    _Pragma("unroll") \
    for (int it_ = 0; it_ < 4; ++it_) \
        GLL(W + boffs + (size_t)it_ * 64 * DIMD + (k0), \
            (char*)(dst) + (tid + it_ * 512) * 16); \
} while (0)

    f32x4 acc[8][4];
#pragma unroll
    for (int i = 0; i < 8; i++)
#pragma unroll
        for (int j = 0; j < 4; j++)
            acc[i][j] = f32x4{0.f, 0.f, 0.f, 0.f};

    BT_STAGE_A(&As[0][0], 0);
    BT_STAGE_B(&Bs[0][0], 0);
    asm volatile("" ::: "memory");
    BT_STAGE_A(&As[1][0], KBK);
    asm volatile("s_waitcnt vmcnt(4)" ::: "memory");
    __builtin_amdgcn_s_barrier();

    auto tile = [&](int kt, ushort_t* Asb, ushort_t* Bsb, ushort_t* Bsn) {
        bf16x8 af0[8], af1[8], bf0[4], bf1[4];

        // ---- P0: A + B[0..1] ksub0; issue B(kt+1); mfma j=0,1 ksub0
#pragma unroll
        for (int i = 0; i < 8; i++)
            af0[i] = *(const bf16x8*)(Asb + (wr * 128 + i * 16 + lrow) * KBK + sw0);
#pragma unroll
        for (int j = 0; j < 2; j++)
            bf0[j] = *(const bf16x8*)(Bsb + (wc * 64 + j * 16 + lrow) * KBK + sw0);
        if (kt + 1 < NKT) BT_STAGE_B(Bsn, (kt + 1) * KBK);
        __builtin_amdgcn_s_barrier();
        asm volatile("s_waitcnt lgkmcnt(0)" ::: "memory");
        __builtin_amdgcn_sched_barrier(0);
        __builtin_amdgcn_s_setprio(1);
#pragma unroll
        for (int i = 0; i < 8; i++)
#pragma unroll
            for (int j = 0; j < 2; j++)
                acc[i][j] = __builtin_amdgcn_mfma_f32_16x16x32_bf16(af0[i], bf0[j], acc[i][j], 0, 0, 0);
        __builtin_amdgcn_s_setprio(0);
        __builtin_amdgcn_s_barrier();

        // ---- P1: B[2..3] ksub0; mfma j=2,3 ksub0
#pragma unroll
        for (int j = 2; j < 4; j++)
            bf0[j] = *(const bf16x8*)(Bsb + (wc * 64 + j * 16 + lrow) * KBK + sw0);
        __builtin_amdgcn_s_barrier();
        asm volatile("s_waitcnt lgkmcnt(0)" ::: "memory");
        __builtin_amdgcn_sched_barrier(0);
        __builtin_amdgcn_s_setprio(1);
#pragma unroll
        for (int i = 0; i < 8; i++)
#pragma unroll
            for (int j = 2; j < 4; j++)
                acc[i][j] = __builtin_amdgcn_mfma_f32_16x16x32_bf16(af0[i], bf0[j], acc[i][j], 0, 0, 0);
        __builtin_amdgcn_s_setprio(0);
        __builtin_amdgcn_s_barrier();

        // ---- P2: A + B[0..1] ksub1; mfma j=0,1 ksub1
#pragma unroll
        for (int i = 0; i < 8; i++)
            af1[i] = *(const bf16x8*)(Asb + (wr * 128 + i * 16 + lrow) * KBK + sw1);
#pragma unroll
        for (int j = 0; j < 2; j++)
            bf1[j] = *(const bf16x8*)(Bsb + (wc * 64 + j * 16 + lrow) * KBK + sw1);
        __builtin_amdgcn_s_barrier();
        asm volatile("s_waitcnt lgkmcnt(0)" ::: "memory");
        __builtin_amdgcn_sched_barrier(0);
        __builtin_amdgcn_s_setprio(1);
#pragma unroll
        for (int i = 0; i < 8; i++)
#pragma unroll
            for (int j = 0; j < 2; j++)
                acc[i][j] = __builtin_amdgcn_mfma_f32_16x16x32_bf16(af1[i], bf1[j], acc[i][j], 0, 0, 0);
        __builtin_amdgcn_s_setprio(0);
        __builtin_amdgcn_s_barrier();

        // ---- P3: B[2..3] ksub1; issue A(kt+2) (A reads fully drained at
        //      P2 lgkm + P2-end barrier); mfma j=2,3 ksub1; boundary
#pragma unroll
        for (int j = 2; j < 4; j++)
            bf1[j] = *(const bf16x8*)(Bsb + (wc * 64 + j * 16 + lrow) * KBK + sw1);
        if (kt + 2 < NKT) BT_STAGE_A(Asb, (kt + 2) * KBK);
        __builtin_amdgcn_s_barrier();
        asm volatile("s_waitcnt lgkmcnt(0)" ::: "memory");
        __builtin_amdgcn_sched_barrier(0);
        __builtin_amdgcn_s_setprio(1);
#pragma unroll
        for (int i = 0; i < 8; i++)
#pragma unroll
            for (int j = 2; j < 4; j++)
                acc[i][j] = __builtin_amdgcn_mfma_f32_16x16x32_bf16(af1[i], bf1[j], acc[i][j], 0, 0, 0);
        __builtin_amdgcn_s_setprio(0);
        if (kt < NKT - 2)       asm volatile("s_waitcnt vmcnt(4)" ::: "memory");
        else if (kt == NKT - 2) asm volatile("s_waitcnt vmcnt(0)" ::: "memory");
        __builtin_amdgcn_s_barrier();
    };

    for (int m = 0; m < NKT / 2; ++m) {
        tile(2 * m,     &As[0][0], &Bs[0][0], &Bs[1][0]);
        tile(2 * m + 1, &As[1][0], &Bs[1][0], &Bs[0][0]);
    }

#pragma unroll
    for (int i = 0; i < 8; i++)
#pragma unroll
        for (int j = 0; j < 4; j++)
#pragma unroll
            for (int r = 0; r < 4; r++) {
                const int row = row0 + wr * 128 + i * 16 + kq * 4 + r;
                const int col = e0 + wc * 64 + j * 16 + lrow;
                Of[(size_t)row * DIMD + col] = acc[i][j][r];
            }
#undef BT_STAGE_A
#undef BT_STAGE_B
}

// ---------------------------------------------------------------------------
// Scan across chunks, register-resident. Thread per (b, d).
// 64-thread blocks -> 64 blocks spread across CUs.
// ---------------------------------------------------------------------------
__global__ __launch_bounds__(64)
void chunk_scan(float* __restrict__ cs, const float* __restrict__ td)
{
    const int idx = blockIdx.x * 64 + threadIdx.x;   // 4096 threads
    const int d = idx & (DIMD - 1);
    const int b = idx >> 10;

    const float w      = -__expf(td[d]);
    const float decayL = __expf(w * (float)CHUNK);

    float v[NCHUNK];
    const size_t base = ((size_t)b * NCHUNK) * DIMD + d;
#pragma unroll
    for (int c = 0; c < NCHUNK; c++)
        v[c] = cs[base + (size_t)c * DIMD];

    float st = 0.f;
#pragma unroll
    for (int c = 0; c < NCHUNK; c++) {
        const float sc = v[c];
        v[c] = st;
        st = decayL * st + sc;
    }

#pragma unroll
    for (int c = 0; c < NCHUNK; c++)
        cs[base + (size_t)c * DIMD] = v[c];
}

// ---------------------------------------------------------------------------
// Emit: out_pre = r*(state + eu*kv); state = decay*state + kv. 8 d's/thread.
// 64-thread blocks: 512 workgroups -> all 256 CUs engaged (was 128 WGs).
// ---------------------------------------------------------------------------
__global__ __launch_bounds__(64)
void emit(const ushort_t* __restrict__ kvb, const ushort_t* __restrict__ rb,
          const float* __restrict__ td, const float* __restrict__ tf,
          const float* __restrict__ cs, ushort_t* __restrict__ op)
{
    const int t  = blockIdx.x * 64 + threadIdx.x;    // 32768 threads
    const int d0 = (t & (DIMD / 8 - 1)) * 8;
    const int bc = t >> 7;
    const int c  = bc & (NCHUNK - 1);
    const int b  = bc >> 6;

    float decay[8], eu[8], st[8];
#pragma unroll
    for (int j = 0; j < 8; j++) {
        decay[j] = __expf(-__expf(td[d0 + j]));
        eu[j]    = __expf(tf[d0 + j]);
    }
    const float* csp = cs + ((size_t)bc * DIMD + d0);
    const float4 s0 = *(const float4*)csp;
    const float4 s1 = *(const float4*)(csp + 4);
    st[0] = s0.x; st[1] = s0.y; st[2] = s0.z; st[3] = s0.w;
    st[4] = s1.x; st[5] = s1.y; st[6] = s1.z; st[7] = s1.w;

    size_t off = ((size_t)b * SEQ + (size_t)c * CHUNK) * DIMD + d0;
#pragma unroll 8
    for (int i = 0; i < CHUNK; i++) {
        const u16x8 kv8 = *(const u16x8*)(kvb + off);
        const u16x8 r8  = *(const u16x8*)(rb + off);
        u16x8 o8;
#pragma unroll
        for (int j = 0; j < 8; j++) {
            const float kv = b2f(kv8[j]);
            o8[j] = f2b(b2f(r8[j]) * (st[j] + eu[j] * kv));
            st[j] = decay[j] * st[j] + kv;
        }
        *(u16x8*)(op + off) = o8;
        off += DIMD;
    }
}

// ---------------------------------------------------------------------------
// ws: xb/pbuf 32 MiB + weights 8 MiB + cs 1 MiB = 41 MiB.
// d_out (64 MiB f32) doubles as kvb+rb scratch (dead before final GEMM).
// ---------------------------------------------------------------------------
extern "C" void kernel_launch(void* const* d_in, const int* in_sizes, int n_in,
                              void* d_out, int out_size, void* d_ws, size_t ws_size,
                              hipStream_t stream)
{
    const float* x  = (const float*)d_in[0];
    const float* Wk = (const float*)d_in[1];
    const float* Wv = (const float*)d_in[2];
    const float* Wr = (const float*)d_in[3];
    const float* Wo = (const float*)d_in[4];
    const float* td = (const float*)d_in[5];
    const float* tf = (const float*)d_in[6];

    ushort_t* xb  = (ushort_t*)d_ws;                       // 32 MiB; reused as pbuf
    ushort_t* Wb  = xb + (size_t)NTOK * DIMD;              // 8 MiB (4 matrices)
    ushort_t* Wkb = Wb;
    ushort_t* Wvb = Wb + (size_t)DIMD * DIMD;
    ushort_t* Wrb = Wb + 2 * (size_t)DIMD * DIMD;
    ushort_t* Wob = Wb + 3 * (size_t)DIMD * DIMD;
    float*    cs  = (float*)(Wb + 4 * (size_t)DIMD * DIMD); // 1 MiB
    ushort_t* pbuf = xb;

    ushort_t* kvb = (ushort_t*)d_out;                      // 32 MiB scratch
    ushort_t* rb  = kvb + (size_t)NTOK * DIMD;             // 32 MiB scratch
    float*    out = (float*)d_out;

    // 0) conversions
    conv_f2b<<<NTOK * DIMD / 8 / 256, 256, 0, stream>>>(x, xb, NTOK * DIMD / 8);
    conv_w<<<dim3(DIMD * DIMD / 8 / 256, 4), 256, 0, stream>>>(Wk, Wv, Wr, Wo, Wb);

    // 1) fused kv & r projections + per-chunk aggregates
    gemm_kvr<<<dim3(NTOK / 256, DIMD / 64), 512, 0, stream>>>(
        xb, Wkb, Wvb, Wrb, td, kvb, rb, cs);

    // 2) scan over chunk boundaries
    chunk_scan<<<BATCH * DIMD / 64, 64, 0, stream>>>(cs, td);

    // 3) out_pre -> pbuf (xb region)
    emit<<<BATCH * NCHUNK * (DIMD / 8) / 64, 64, 0, stream>>>(
        kvb, rb, td, tf, cs, pbuf);

    // 4) out = out_pre @ Wo^T (f32 epilogue, overwrites d_out)
    gemm_bt<<<dim3(NTOK / 256, DIMD / 256), 512, 0, stream>>>(pbuf, Wob, out);
}

// Round 2
// 308.459 us; speedup vs baseline: 1.0195x; 1.0032x over previous
//
#include <hip/hip_runtime.h>
#include <hip/hip_bf16.h>

// Problem constants
#define DIMD   1024
#define BATCH  4
#define SEQ    4096
#define NTOK   (BATCH * SEQ)   // 16384
#define CHUNK  64              // recurrence chunk length
#define NCHUNK (SEQ / CHUNK)   // 64

// K-tiling for the MFMA GEMMs: 64-deep K tiles, 16 tiles total.
#define KBK    64
#define NKT    (DIMD / KBK)

typedef unsigned short ushort_t;
typedef __attribute__((ext_vector_type(8))) __bf16   bf16x8;
typedef __attribute__((ext_vector_type(4))) float    f32x4;
typedef __attribute__((ext_vector_type(8))) ushort_t u16x8;

__device__ __forceinline__ float b2f(ushort_t u) {
    union { unsigned int i; float f; } x;
    x.i = ((unsigned int)u) << 16;
    return x.f;
}

__device__ __forceinline__ ushort_t f2b(float f) {
    union { float f; unsigned int i; } x;
    x.f = f;
    unsigned int r = x.i + 0x7fffu + ((x.i >> 16) & 1u);  // RNE
    return (ushort_t)(r >> 16);
}

// 16B global->LDS direct copy. LDS dest must be wave-uniform-base + lane*16
// (linear); swizzling is done on the per-lane GLOBAL source address.
#define GLL(gsrc, ldst) __builtin_amdgcn_global_load_lds( \
    (__attribute__((address_space(1))) void*)(gsrc), \
    (__attribute__((address_space(3))) void*)(ldst), 16, 0, 0)

// ---------------------------------------------------------------------------
// f32 -> bf16, 8 elem/thread, 16B stores.
// ---------------------------------------------------------------------------
__global__ __launch_bounds__(256)
void conv_f2b(const float* __restrict__ src, ushort_t* __restrict__ dst, int n8)
{
    const int i = blockIdx.x * 256 + threadIdx.x;
    if (i >= n8) return;
    const float4* s4 = (const float4*)src;
    const float4 a = s4[i * 2];
    const float4 b = s4[i * 2 + 1];
    u16x8 o;
    o[0] = f2b(a.x); o[1] = f2b(a.y); o[2] = f2b(a.z); o[3] = f2b(a.w);
    o[4] = f2b(b.x); o[5] = f2b(b.y); o[6] = f2b(b.z); o[7] = f2b(b.w);
    *(u16x8*)(dst + (size_t)i * 8) = o;
}

// All 4 weight matrices in one launch; blockIdx.y selects the matrix.
__global__ __launch_bounds__(256)
void conv_w(const float* __restrict__ W0, const float* __restrict__ W1,
            const float* __restrict__ W2, const float* __restrict__ W3,
            ushort_t* __restrict__ dst)
{
    const int m = blockIdx.y;
    const float* src = (m == 0) ? W0 : (m == 1) ? W1 : (m == 2) ? W2 : W3;
    const int i = blockIdx.x * 256 + threadIdx.x;
    const float4* s4 = (const float4*)src;
    const float4 a = s4[i * 2];
    const float4 b = s4[i * 2 + 1];
    u16x8 o;
    o[0] = f2b(a.x); o[1] = f2b(a.y); o[2] = f2b(a.z); o[3] = f2b(a.w);
    o[4] = f2b(b.x); o[5] = f2b(b.y); o[6] = f2b(b.z); o[7] = f2b(b.w);
    *(u16x8*)(dst + (size_t)m * DIMD * DIMD + (size_t)i * 8) = o;
}

// ---------------------------------------------------------------------------
// Fused k,v projection GEMM. Block 256x128, 512 threads, 8 waves each owning
// a 64x64 output tile of BOTH matrices (needed together for kv = k*v and the
// per-chunk decay-weighted sums). 4 phases/K-tile, 16 MFMA each,
// reads/MFMA = 0.375 (template density). LDS 128 KB (A 2x32K, Bk/Bv 2x16K).
// Counted vmcnt(4): A prefetched 2 tiles ahead, B 1 ahead; never drain to 0
// mid-loop. XOR swizzle on global source + LDS read (involution, rule 21).
// ---------------------------------------------------------------------------
__global__ __launch_bounds__(512, 2)
void gemm_kv(const ushort_t* __restrict__ A,
             const ushort_t* __restrict__ Wk,
             const ushort_t* __restrict__ Wv,
             const float* __restrict__ td,
             ushort_t* __restrict__ Okv,
             float* __restrict__ cs)
{
    __shared__ __align__(16) ushort_t As[2][256 * KBK];  // 2 x 32 KB
    __shared__ __align__(16) ushort_t Bk[2][128 * KBK];  // 2 x 16 KB
    __shared__ __align__(16) ushort_t Bv[2][128 * KBK];  // 2 x 16 KB

    const int tid  = threadIdx.x;
    const int lane = tid & 63;
    const int wv   = tid >> 6;        // 0..7
    const int wr   = wv >> 1;         // 0..3 : 64-row chunk (= seq chunk)
    const int wc   = wv & 1;          // 0..1 : 64-col half
    const int lrow = lane & 15;
    const int kq   = lane >> 4;
    const int s8   = lrow & 7;
    const int sw0  = (kq ^ s8) * 8;        // swizzled elem offset, ksub=0
    const int sw1  = ((kq + 4) ^ s8) * 8;  // swizzled elem offset, ksub=1

    const int row0 = blockIdx.x * 256;
    const int e0   = blockIdx.y * 128;

    // Staging: dest chunk (row, q) <- global (row, q ^ (row&7)).
    const int r_  = tid >> 3;                       // 0..63
    const int q_  = ((tid & 7) ^ (r_ & 7)) * 8;
    const size_t aoffs = (size_t)(row0 + r_) * DIMD + q_;
    const size_t boffs = (size_t)(e0 + r_) * DIMD + q_;

#define KV_STAGE_A(dst, k0) do { \
    _Pragma("unroll") \
    for (int it_ = 0; it_ < 4; ++it_) \
        GLL(A + aoffs + (size_t)it_ * 64 * DIMD + (k0), \
            (char*)(dst) + (tid + it_ * 512) * 16); \
} while (0)

#define KV_STAGE_B(Wp, dst, k0) do { \
    _Pragma("unroll") \
    for (int it_ = 0; it_ < 2; ++it_) \
        GLL((Wp) + boffs + (size_t)it_ * 64 * DIMD + (k0), \
            (char*)(dst) + (tid + it_ * 512) * 16); \
} while (0)

    f32x4 ak[4][4], av[4][4];
#pragma unroll
    for (int i = 0; i < 4; i++)
#pragma unroll
        for (int j = 0; j < 4; j++) {
            ak[i][j] = f32x4{0.f, 0.f, 0.f, 0.f};
            av[i][j] = f32x4{0.f, 0.f, 0.f, 0.f};
        }

    // Prologue: A0, B0, A1 in flight; drain A0+B0, keep A1 (vmcnt(4)).
    KV_STAGE_A(&As[0][0], 0);
    KV_STAGE_B(Wk, &Bk[0][0], 0);
    KV_STAGE_B(Wv, &Bv[0][0], 0);
    asm volatile("" ::: "memory");
    KV_STAGE_A(&As[1][0], KBK);
    asm volatile("s_waitcnt vmcnt(4)" ::: "memory");
    __builtin_amdgcn_s_barrier();

    auto tile = [&](int kt, ushort_t* Asb, ushort_t* Bkb, ushort_t* Bvb,
                    ushort_t* Bkn, ushort_t* Bvn) {
        bf16x8 af0[4], af1[4], b0[4], b1[4], c0[4], c1[4];

        // ---- P0: read A + Bk (ksub0); issue Bk(kt+1); 16 MFMA k-ksub0
#pragma unroll
        for (int i = 0; i < 4; i++)
            af0[i] = *(const bf16x8*)(Asb + (wr * 64 + i * 16 + lrow) * KBK + sw0);
#pragma unroll
        for (int j = 0; j < 4; j++)
            b0[j] = *(const bf16x8*)(Bkb + (wc * 64 + j * 16 + lrow) * KBK + sw0);
        if (kt + 1 < NKT) KV_STAGE_B(Wk, Bkn, (kt + 1) * KBK);
        __builtin_amdgcn_s_barrier();
        asm volatile("s_waitcnt lgkmcnt(0)" ::: "memory");
        __builtin_amdgcn_sched_barrier(0);
        __builtin_amdgcn_s_setprio(1);
#pragma unroll
        for (int i = 0; i < 4; i++)
#pragma unroll
            for (int j = 0; j < 4; j++)
                ak[i][j] = __builtin_amdgcn_mfma_f32_16x16x32_bf16(af0[i], b0[j], ak[i][j], 0, 0, 0);
        __builtin_amdgcn_s_setprio(0);
        __builtin_amdgcn_s_barrier();

        // ---- P1: read Bv (ksub0); issue Bv(kt+1); 16 MFMA v-ksub0
#pragma unroll
        for (int j = 0; j < 4; j++)
            c0[j] = *(const bf16x8*)(Bvb + (wc * 64 + j * 16 + lrow) * KBK + sw0);
        if (kt + 1 < NKT) KV_STAGE_B(Wv, Bvn, (kt + 1) * KBK);
        __builtin_amdgcn_s_barrier();
        asm volatile("s_waitcnt lgkmcnt(0)" ::: "memory");
        __builtin_amdgcn_sched_barrier(0);
        __builtin_amdgcn_s_setprio(1);
#pragma unroll
        for (int i = 0; i < 4; i++)
#pragma unroll
            for (int j = 0; j < 4; j++)
                av[i][j] = __builtin_amdgcn_mfma_f32_16x16x32_bf16(af0[i], c0[j], av[i][j], 0, 0, 0);
        __builtin_amdgcn_s_setprio(0);
        __builtin_amdgcn_s_barrier();

        // ---- P2: read A + Bk (ksub1); 16 MFMA k-ksub1
#pragma unroll
        for (int i = 0; i < 4; i++)
            af1[i] = *(const bf16x8*)(Asb + (wr * 64 + i * 16 + lrow) * KBK + sw1);
#pragma unroll
        for (int j = 0; j < 4; j++)
            b1[j] = *(const bf16x8*)(Bkb + (wc * 64 + j * 16 + lrow) * KBK + sw1);
        __builtin_amdgcn_s_barrier();
        asm volatile("s_waitcnt lgkmcnt(0)" ::: "memory");
        __builtin_amdgcn_sched_barrier(0);
        __builtin_amdgcn_s_setprio(1);
#pragma unroll
        for (int i = 0; i < 4; i++)
#pragma unroll
            for (int j = 0; j < 4; j++)
                ak[i][j] = __builtin_amdgcn_mfma_f32_16x16x32_bf16(af1[i], b1[j], ak[i][j], 0, 0, 0);
        __builtin_amdgcn_s_setprio(0);
        __builtin_amdgcn_s_barrier();

        // ---- P3: read Bv (ksub1); issue A(kt+2) into vacated A buffer
        //      (all af1 reads drained at P2 lgkm + barrier); 16 MFMA v-ksub1
#pragma unroll
        for (int j = 0; j < 4; j++)
            c1[j] = *(const bf16x8*)(Bvb + (wc * 64 + j * 16 + lrow) * KBK + sw1);
        if (kt + 2 < NKT) KV_STAGE_A(Asb, (kt + 2) * KBK);
        __builtin_amdgcn_s_barrier();
        asm volatile("s_waitcnt lgkmcnt(0)" ::: "memory");
        __builtin_amdgcn_sched_barrier(0);
        __builtin_amdgcn_s_setprio(1);
#pragma unroll
        for (int i = 0; i < 4; i++)
#pragma unroll
            for (int j = 0; j < 4; j++)
                av[i][j] = __builtin_amdgcn_mfma_f32_16x16x32_bf16(af1[i], c1[j], av[i][j], 0, 0, 0);
        __builtin_amdgcn_s_setprio(0);
        // Drain A(kt+1)+B(kt+1); keep A(kt+2) (newest 4) in flight.
        if (kt < NKT - 2)       asm volatile("s_waitcnt vmcnt(4)" ::: "memory");
        else if (kt == NKT - 2) asm volatile("s_waitcnt vmcnt(0)" ::: "memory");
        __builtin_amdgcn_s_barrier();
    };

    for (int m = 0; m < NKT / 2; ++m) {
        tile(2 * m,     &As[0][0], &Bk[0][0], &Bv[0][0], &Bk[1][0], &Bv[1][0]);
        tile(2 * m + 1, &As[1][0], &Bk[1][0], &Bv[1][0], &Bk[0][0], &Bv[0][0]);
    }

    // Epilogue 1: kv store. C/D layout: col = lane&15, row = quad*4+reg.
#pragma unroll
    for (int i = 0; i < 4; i++)
#pragma unroll
        for (int j = 0; j < 4; j++)
#pragma unroll
            for (int r = 0; r < 4; r++) {
                const int row = row0 + wr * 64 + i * 16 + kq * 4 + r;
                const int col = e0 + wc * 64 + j * 16 + lrow;
                Okv[(size_t)row * DIMD + col] = f2b(ak[i][j][r] * av[i][j][r]);
            }

    // Epilogue 2: per-chunk weighted sum  s(d) = sum_row decay^(63-row) k*v.
    // Wave wr owns exactly one 64-token chunk.
#pragma unroll
    for (int j = 0; j < 4; j++) {
        const int col = e0 + wc * 64 + j * 16 + lrow;
        const float w = -__expf(td[col]);
        float s = 0.f;
#pragma unroll
        for (int i = 0; i < 4; i++)
#pragma unroll
            for (int r = 0; r < 4; r++) {
                const int rl = i * 16 + kq * 4 + r;           // 0..63
                s += __expf(w * (float)(63 - rl)) * ak[i][j][r] * av[i][j][r];
            }
        s += __shfl_xor(s, 16);
        s += __shfl_xor(s, 32);
        if (kq == 0) {
            const int gchunk = (row0 >> 6) + wr;              // global chunk id
            cs[(size_t)gchunk * DIMD + col] = s;
        }
    }
#undef KV_STAGE_A
#undef KV_STAGE_B
}

// ---------------------------------------------------------------------------
// r projection: 256x256 template GEMM with sigmoid -> bf16 epilogue.
// Same 4-phase counted-vmcnt pipeline + swizzle as gemm_bt.
// ---------------------------------------------------------------------------
__global__ __launch_bounds__(512, 2)
void gemm_rs(const ushort_t* __restrict__ A,
             const ushort_t* __restrict__ W,
             ushort_t* __restrict__ Or)
{
    __shared__ __align__(16) ushort_t As[2][256 * KBK];  // 2 x 32 KB
    __shared__ __align__(16) ushort_t Bs[2][256 * KBK];  // 2 x 32 KB

    const int tid  = threadIdx.x;
    const int lane = tid & 63;
    const int wv   = tid >> 6;
    const int wr   = wv >> 2;         // 0..1 : 128-row half
    const int wc   = wv & 3;          // 0..3 : 64-col quarter
    const int lrow = lane & 15;
    const int kq   = lane >> 4;
    const int s8   = lrow & 7;
    const int sw0  = (kq ^ s8) * 8;
    const int sw1  = ((kq + 4) ^ s8) * 8;

    const int row0 = blockIdx.x * 256;
    const int e0   = blockIdx.y * 256;

    const int r_  = tid >> 3;
    const int q_  = ((tid & 7) ^ (r_ & 7)) * 8;
    const size_t aoffs = (size_t)(row0 + r_) * DIMD + q_;
    const size_t boffs = (size_t)(e0 + r_) * DIMD + q_;

#define RS_STAGE_A(dst, k0) do { \
    _Pragma("unroll") \
    for (int it_ = 0; it_ < 4; ++it_) \
        GLL(A + aoffs + (size_t)it_ * 64 * DIMD + (k0), \
            (char*)(dst) + (tid + it_ * 512) * 16); \
} while (0)

#define RS_STAGE_B(dst, k0) do { \
    _Pragma("unroll") \
    for (int it_ = 0; it_ < 4; ++it_) \
        GLL(W + boffs + (size_t)it_ * 64 * DIMD + (k0), \
            (char*)(dst) + (tid + it_ * 512) * 16); \
} while (0)

    f32x4 acc[8][4];
#pragma unroll
    for (int i = 0; i < 8; i++)
#pragma unroll
        for (int j = 0; j < 4; j++)
            acc[i][j] = f32x4{0.f, 0.f, 0.f, 0.f};

    RS_STAGE_A(&As[0][0], 0);
    RS_STAGE_B(&Bs[0][0], 0);
    asm volatile("" ::: "memory");
    RS_STAGE_A(&As[1][0], KBK);
    asm volatile("s_waitcnt vmcnt(4)" ::: "memory");
    __builtin_amdgcn_s_barrier();

    auto tile = [&](int kt, ushort_t* Asb, ushort_t* Bsb, ushort_t* Bsn) {
        bf16x8 af0[8], af1[8], bf0[4], bf1[4];

        // ---- P0
#pragma unroll
        for (int i = 0; i < 8; i++)
            af0[i] = *(const bf16x8*)(Asb + (wr * 128 + i * 16 + lrow) * KBK + sw0);
#pragma unroll
        for (int j = 0; j < 2; j++)
            bf0[j] = *(const bf16x8*)(Bsb + (wc * 64 + j * 16 + lrow) * KBK + sw0);
        if (kt + 1 < NKT) RS_STAGE_B(Bsn, (kt + 1) * KBK);
        __builtin_amdgcn_s_barrier();
        asm volatile("s_waitcnt lgkmcnt(0)" ::: "memory");
        __builtin_amdgcn_sched_barrier(0);
        __builtin_amdgcn_s_setprio(1);
#pragma unroll
        for (int i = 0; i < 8; i++)
#pragma unroll
            for (int j = 0; j < 2; j++)
                acc[i][j] = __builtin_amdgcn_mfma_f32_16x16x32_bf16(af0[i], bf0[j], acc[i][j], 0, 0, 0);
        __builtin_amdgcn_s_setprio(0);
        __builtin_amdgcn_s_barrier();

        // ---- P1
#pragma unroll
        for (int j = 2; j < 4; j++)
            bf0[j] = *(const bf16x8*)(Bsb + (wc * 64 + j * 16 + lrow) * KBK + sw0);
        __builtin_amdgcn_s_barrier();
        asm volatile("s_waitcnt lgkmcnt(0)" ::: "memory");
        __builtin_amdgcn_sched_barrier(0);
        __builtin_amdgcn_s_setprio(1);
#pragma unroll
        for (int i = 0; i < 8; i++)
#pragma unroll
            for (int j = 2; j < 4; j++)
                acc[i][j] = __builtin_amdgcn_mfma_f32_16x16x32_bf16(af0[i], bf0[j], acc[i][j], 0, 0, 0);
        __builtin_amdgcn_s_setprio(0);
        __builtin_amdgcn_s_barrier();

        // ---- P2
#pragma unroll
        for (int i = 0; i < 8; i++)
            af1[i] = *(const bf16x8*)(Asb + (wr * 128 + i * 16 + lrow) * KBK + sw1);
#pragma unroll
        for (int j = 0; j < 2; j++)
            bf1[j] = *(const bf16x8*)(Bsb + (wc * 64 + j * 16 + lrow) * KBK + sw1);
        __builtin_amdgcn_s_barrier();
        asm volatile("s_waitcnt lgkmcnt(0)" ::: "memory");
        __builtin_amdgcn_sched_barrier(0);
        __builtin_amdgcn_s_setprio(1);
#pragma unroll
        for (int i = 0; i < 8; i++)
#pragma unroll
            for (int j = 0; j < 2; j++)
                acc[i][j] = __builtin_amdgcn_mfma_f32_16x16x32_bf16(af1[i], bf1[j], acc[i][j], 0, 0, 0);
        __builtin_amdgcn_s_setprio(0);
        __builtin_amdgcn_s_barrier();

        // ---- P3
#pragma unroll
        for (int j = 2; j < 4; j++)
            bf1[j] = *(const bf16x8*)(Bsb + (wc * 64 + j * 16 + lrow) * KBK + sw1);
        if (kt + 2 < NKT) RS_STAGE_A(Asb, (kt + 2) * KBK);
        __builtin_amdgcn_s_barrier();
        asm volatile("s_waitcnt lgkmcnt(0)" ::: "memory");
        __builtin_amdgcn_sched_barrier(0);
        __builtin_amdgcn_s_setprio(1);
#pragma unroll
        for (int i = 0; i < 8; i++)
#pragma unroll
            for (int j = 2; j < 4; j++)
                acc[i][j] = __builtin_amdgcn_mfma_f32_16x16x32_bf16(af1[i], bf1[j], acc[i][j], 0, 0, 0);
        __builtin_amdgcn_s_setprio(0);
        if (kt < NKT - 2)       asm volatile("s_waitcnt vmcnt(4)" ::: "memory");
        else if (kt == NKT - 2) asm volatile("s_waitcnt vmcnt(0)" ::: "memory");
        __builtin_amdgcn_s_barrier();
    };

    for (int m = 0; m < NKT / 2; ++m) {
        tile(2 * m,     &As[0][0], &Bs[0][0], &Bs[1][0]);
        tile(2 * m + 1, &As[1][0], &Bs[1][0], &Bs[0][0]);
    }

#pragma unroll
    for (int i = 0; i < 8; i++)
#pragma unroll
        for (int j = 0; j < 4; j++)
#pragma unroll
            for (int r = 0; r < 4; r++) {
                const int row = row0 + wr * 128 + i * 16 + kq * 4 + r;
                const int col = e0 + wc * 64 + j * 16 + lrow;
                Or[(size_t)row * DIMD + col] =
                    f2b(1.f / (1.f + __expf(-acc[i][j][r])));
            }
#undef RS_STAGE_A
#undef RS_STAGE_B
}

// ---------------------------------------------------------------------------
// Final GEMM: C[n,e] = sum_d A[n,d] * W[e,d], f32 out.
// 256x256 block, 512 threads, 4-phase counted-vmcnt pipeline + swizzle.
// ---------------------------------------------------------------------------
__global__ __launch_bounds__(512, 2)
void gemm_bt(const ushort_t* __restrict__ A,
             const ushort_t* __restrict__ W,
             float* __restrict__ Of)
{
    __shared__ __align__(16) ushort_t As[2][256 * KBK];  // 2 x 32 KB
    __shared__ __align__(16) ushort_t Bs[2][256 * KBK];  // 2 x 32 KB

    const int tid  = threadIdx.x;
    const int lane = tid & 63;
    const int wv   = tid >> 6;
    const int wr   = wv >> 2;
    const int wc   = wv & 3;
    const int lrow = lane & 15;
    const int kq   = lane >> 4;
    const int s8   = lrow & 7;
    const int sw0  = (kq ^ s8) * 8;
    const int sw1  = ((kq + 4) ^ s8) * 8;

    const int row0 = blockIdx.x * 256;
    const int e0   = blockIdx.y * 256;

    const int r_  = tid >> 3;
    const int q_  = ((tid & 7) ^ (r_ & 7)) * 8;
    const size_t aoffs = (size_t)(row0 + r_) * DIMD + q_;
    const size_t boffs = (size_t)(e0 + r_) * DIMD + q_;

#define BT_STAGE_A(dst, k0) do { \
    _Pragma("unroll") \
    for (int it_ = 0; it_ < 4; ++it_) \
        GLL(A + aoffs + (size_t)it_ * 64 * DIMD + (k0), \
            (char*)(dst) + (tid + it_ * 512) * 16); \
} while (0)

#define BT_STAGE_B(dst, k0) do { \
    _Pragma("unroll") \
    for (int it_ = 0; it_ < 4; ++it_) \
        GLL(W + boffs + (size_t)it_ * 64 * DIMD + (k0), \
            (char*)(dst) + (tid + it_ * 512) * 16); \
} while (0)

    f32x4 acc[8][4];
#pragma unroll
    for (int i = 0; i < 8; i++)
#pragma unroll
        for (int j = 0; j < 4; j++)
            acc[i][j] = f32x4{0.f, 0.f, 0.f, 0.f};

    BT_STAGE_A(&As[0][0], 0);
    BT_STAGE_B(&Bs[0][0], 0);
    asm volatile("" ::: "memory");
    BT_STAGE_A(&As[1][0], KBK);
    asm volatile("s_waitcnt vmcnt(4)" ::: "memory");
    __builtin_amdgcn_s_barrier();

    auto tile = [&](int kt, ushort_t* Asb, ushort_t* Bsb, ushort_t* Bsn) {
        bf16x8 af0[8], af1[8], bf0[4], bf1[4];

        // ---- P0
#pragma unroll
        for (int i = 0; i < 8; i++)
            af0[i] = *(const bf16x8*)(Asb + (wr * 128 + i * 16 + lrow) * KBK + sw0);
#pragma unroll
        for (int j = 0; j < 2; j++)
            bf0[j] = *(const bf16x8*)(Bsb + (wc * 64 + j * 16 + lrow) * KBK + sw0);
        if (kt + 1 < NKT) BT_STAGE_B(Bsn, (kt + 1) * KBK);
        __builtin_amdgcn_s_barrier();
        asm volatile("s_waitcnt lgkmcnt(0)" ::: "memory");
        __builtin_amdgcn_sched_barrier(0);
        __builtin_amdgcn_s_setprio(1);
#pragma unroll
        for (int i = 0; i < 8; i++)
#pragma unroll
            for (int j = 0; j < 2; j++)
                acc[i][j] = __builtin_amdgcn_mfma_f32_16x16x32_bf16(af0[i], bf0[j], acc[i][j], 0, 0, 0);
        __builtin_amdgcn_s_setprio(0);
        __builtin_amdgcn_s_barrier();

        // ---- P1
#pragma unroll
        for (int j = 2; j < 4; j++)
            bf0[j] = *(const bf16x8*)(Bsb + (wc * 64 + j * 16 + lrow) * KBK + sw0);
        __builtin_amdgcn_s_barrier();
        asm volatile("s_waitcnt lgkmcnt(0)" ::: "memory");
        __builtin_amdgcn_sched_barrier(0);
        __builtin_amdgcn_s_setprio(1);
#pragma unroll
        for (int i = 0; i < 8; i++)
#pragma unroll
            for (int j = 2; j < 4; j++)
                acc[i][j] = __builtin_amdgcn_mfma_f32_16x16x32_bf16(af0[i], bf0[j], acc[i][j], 0, 0, 0);
        __builtin_amdgcn_s_setprio(0);
        __builtin_amdgcn_s_barrier();

        // ---- P2
#pragma unroll
        for (int i = 0; i < 8; i++)
            af1[i] = *(const bf16x8*)(Asb + (wr * 128 + i * 16 + lrow) * KBK + sw1);
#pragma unroll
        for (int j = 0; j < 2; j++)
            bf1[j] = *(const bf16x8*)(Bsb + (wc * 64 + j * 16 + lrow) * KBK + sw1);
        __builtin_amdgcn_s_barrier();
        asm volatile("s_waitcnt lgkmcnt(0)" ::: "memory");
        __builtin_amdgcn_sched_barrier(0);
        __builtin_amdgcn_s_setprio(1);
#pragma unroll
        for (int i = 0; i < 8; i++)
#pragma unroll
            for (int j = 0; j < 2; j++)
                acc[i][j] = __builtin_amdgcn_mfma_f32_16x16x32_bf16(af1[i], bf1[j], acc[i][j], 0, 0, 0);
        __builtin_amdgcn_s_setprio(0);
        __builtin_amdgcn_s_barrier();

        // ---- P3
#pragma unroll
        for (int j = 2; j < 4; j++)
            bf1[j] = *(const bf16x8*)(Bsb + (wc * 64 + j * 16 + lrow) * KBK + sw1);
        if (kt + 2 < NKT) BT_STAGE_A(Asb, (kt + 2) * KBK);
        __builtin_amdgcn_s_barrier();
        asm volatile("s_waitcnt lgkmcnt(0)" ::: "memory");
        __builtin_amdgcn_sched_barrier(0);
        __builtin_amdgcn_s_setprio(1);
#pragma unroll
        for (int i = 0; i < 8; i++)
#pragma unroll
            for (int j = 2; j < 4; j++)
                acc[i][j] = __builtin_amdgcn_mfma_f32_16x16x32_bf16(af1[i], bf1[j], acc[i][j], 0, 0, 0);
        __builtin_amdgcn_s_setprio(0);
        if (kt < NKT - 2)       asm volatile("s_waitcnt vmcnt(4)" ::: "memory");
        else if (kt == NKT - 2) asm volatile("s_waitcnt vmcnt(0)" ::: "memory");
        __builtin_amdgcn_s_barrier();
    };

    for (int m = 0; m < NKT / 2; ++m) {
        tile(2 * m,     &As[0][0], &Bs[0][0], &Bs[1][0]);
        tile(2 * m + 1, &As[1][0], &Bs[1][0], &Bs[0][0]);
    }

#pragma unroll
    for (int i = 0; i < 8; i++)
#pragma unroll
        for (int j = 0; j < 4; j++)
#pragma unroll
            for (int r = 0; r < 4; r++) {
                const int row = row0 + wr * 128 + i * 16 + kq * 4 + r;
                const int col = e0 + wc * 64 + j * 16 + lrow;
                Of[(size_t)row * DIMD + col] = acc[i][j][r];
            }
#undef BT_STAGE_A
#undef BT_STAGE_B
}

// ---------------------------------------------------------------------------
// Scan across chunks, register-resident. Thread per (b, d).
// ---------------------------------------------------------------------------
__global__ __launch_bounds__(64)
void chunk_scan(float* __restrict__ cs, const float* __restrict__ td)
{
    const int idx = blockIdx.x * 64 + threadIdx.x;   // 4096 threads
    const int d = idx & (DIMD - 1);
    const int b = idx >> 10;

    const float w      = -__expf(td[d]);
    const float decayL = __expf(w * (float)CHUNK);

    float v[NCHUNK];
    const size_t base = ((size_t)b * NCHUNK) * DIMD + d;
#pragma unroll
    for (int c = 0; c < NCHUNK; c++)
        v[c] = cs[base + (size_t)c * DIMD];

    float st = 0.f;
#pragma unroll
    for (int c = 0; c < NCHUNK; c++) {
        const float sc = v[c];
        v[c] = st;
        st = decayL * st + sc;
    }

#pragma unroll
    for (int c = 0; c < NCHUNK; c++)
        cs[base + (size_t)c * DIMD] = v[c];
}

// ---------------------------------------------------------------------------
// Emit: out_pre = r*(state + eu*kv); state = decay*state + kv. 8 d's/thread.
// ---------------------------------------------------------------------------
__global__ __launch_bounds__(64)
void emit(const ushort_t* __restrict__ kvb, const ushort_t* __restrict__ rb,
          const float* __restrict__ td, const float* __restrict__ tf,
          const float* __restrict__ cs, ushort_t* __restrict__ op)
{
    const int t  = blockIdx.x * 64 + threadIdx.x;    // 32768 threads
    const int d0 = (t & (DIMD / 8 - 1)) * 8;
    const int bc = t >> 7;
    const int c  = bc & (NCHUNK - 1);
    const int b  = bc >> 6;

    float decay[8], eu[8], st[8];
#pragma unroll
    for (int j = 0; j < 8; j++) {
        decay[j] = __expf(-__expf(td[d0 + j]));
        eu[j]    = __expf(tf[d0 + j]);
    }
    const float* csp = cs + ((size_t)bc * DIMD + d0);
    const float4 s0 = *(const float4*)csp;
    const float4 s1 = *(const float4*)(csp + 4);
    st[0] = s0.x; st[1] = s0.y; st[2] = s0.z; st[3] = s0.w;
    st[4] = s1.x; st[5] = s1.y; st[6] = s1.z; st[7] = s1.w;

    size_t off = ((size_t)b * SEQ + (size_t)c * CHUNK) * DIMD + d0;
#pragma unroll 8
    for (int i = 0; i < CHUNK; i++) {
        const u16x8 kv8 = *(const u16x8*)(kvb + off);
        const u16x8 r8  = *(const u16x8*)(rb + off);
        u16x8 o8;
#pragma unroll
        for (int j = 0; j < 8; j++) {
            const float kv = b2f(kv8[j]);
            o8[j] = f2b(b2f(r8[j]) * (st[j] + eu[j] * kv));
            st[j] = decay[j] * st[j] + kv;
        }
        *(u16x8*)(op + off) = o8;
        off += DIMD;
    }
}

// ---------------------------------------------------------------------------
// ws: xb/pbuf 32 MiB + weights 8 MiB + cs 1 MiB = 41 MiB.
// d_out (64 MiB f32) doubles as kvb+rb scratch (dead before final GEMM).
// ---------------------------------------------------------------------------
extern "C" void kernel_launch(void* const* d_in, const int* in_sizes, int n_in,
                              void* d_out, int out_size, void* d_ws, size_t ws_size,
                              hipStream_t stream)
{
    const float* x  = (const float*)d_in[0];
    const float* Wk = (const float*)d_in[1];
    const float* Wv = (const float*)d_in[2];
    const float* Wr = (const float*)d_in[3];
    const float* Wo = (const float*)d_in[4];
    const float* td = (const float*)d_in[5];
    const float* tf = (const float*)d_in[6];

    ushort_t* xb  = (ushort_t*)d_ws;                       // 32 MiB; reused as pbuf
    ushort_t* Wb  = xb + (size_t)NTOK * DIMD;              // 8 MiB (4 matrices)
    ushort_t* Wkb = Wb;
    ushort_t* Wvb = Wb + (size_t)DIMD * DIMD;
    ushort_t* Wrb = Wb + 2 * (size_t)DIMD * DIMD;
    ushort_t* Wob = Wb + 3 * (size_t)DIMD * DIMD;
    float*    cs  = (float*)(Wb + 4 * (size_t)DIMD * DIMD); // 1 MiB
    ushort_t* pbuf = xb;

    ushort_t* kvb = (ushort_t*)d_out;                      // 32 MiB scratch
    ushort_t* rb  = kvb + (size_t)NTOK * DIMD;             // 32 MiB scratch
    float*    out = (float*)d_out;

    // 0) conversions
    conv_f2b<<<NTOK * DIMD / 8 / 256, 256, 0, stream>>>(x, xb, NTOK * DIMD / 8);
    conv_w<<<dim3(DIMD * DIMD / 8 / 256, 4), 256, 0, stream>>>(Wk, Wv, Wr, Wo, Wb);

    // 1) fused kv projection + per-chunk aggregates
    gemm_kv<<<dim3(NTOK / 256, DIMD / 128), 512, 0, stream>>>(
        xb, Wkb, Wvb, td, kvb, cs);

    // 1b) r projection (sigmoid fused)
    gemm_rs<<<dim3(NTOK / 256, DIMD / 256), 512, 0, stream>>>(xb, Wrb, rb);

    // 2) scan over chunk boundaries
    chunk_scan<<<BATCH * DIMD / 64, 64, 0, stream>>>(cs, td);

    // 3) out_pre -> pbuf (xb region)
    emit<<<BATCH * NCHUNK * (DIMD / 8) / 64, 64, 0, stream>>>(
        kvb, rb, td, tf, cs, pbuf);

    // 4) out = out_pre @ Wo^T (f32 epilogue, overwrites d_out)
    gemm_bt<<<dim3(NTOK / 256, DIMD / 256), 512, 0, stream>>>(pbuf, Wob, out);
}

// Round 3
// 306.752 us; speedup vs baseline: 1.0252x; 1.0056x over previous
//
#include <hip/hip_runtime.h>
#include <hip/hip_bf16.h>

// Problem constants
#define DIMD   1024
#define BATCH  4
#define SEQ    4096
#define NTOK   (BATCH * SEQ)   // 16384
#define CHUNK  64              // recurrence chunk length
#define NCHUNK (SEQ / CHUNK)   // 64

// K-tiling for the MFMA GEMMs: 64-deep K tiles, 16 tiles total.
#define KBK    64
#define NKT    (DIMD / KBK)

typedef unsigned short ushort_t;
typedef __attribute__((ext_vector_type(8))) __bf16   bf16x8;
typedef __attribute__((ext_vector_type(4))) float    f32x4;
typedef __attribute__((ext_vector_type(8))) ushort_t u16x8;

__device__ __forceinline__ float b2f(ushort_t u) {
    union { unsigned int i; float f; } x;
    x.i = ((unsigned int)u) << 16;
    return x.f;
}

__device__ __forceinline__ ushort_t f2b(float f) {
    union { float f; unsigned int i; } x;
    x.f = f;
    unsigned int r = x.i + 0x7fffu + ((x.i >> 16) & 1u);  // RNE
    return (ushort_t)(r >> 16);
}

// 16B global->LDS direct copy. LDS dest must be wave-uniform-base + lane*16
// (linear); swizzling is done on the per-lane GLOBAL source address.
#define GLL(gsrc, ldst) __builtin_amdgcn_global_load_lds( \
    (__attribute__((address_space(1))) void*)(gsrc), \
    (__attribute__((address_space(3))) void*)(ldst), 16, 0, 0)

// ---------------------------------------------------------------------------
// All f32->bf16 conversions in ONE launch: x (8192 blocks) + 4 weight
// matrices (2048 blocks). 8 elem/thread, 16B stores.
// ---------------------------------------------------------------------------
__global__ __launch_bounds__(256)
void conv_all(const float* __restrict__ x,
              const float* __restrict__ W0, const float* __restrict__ W1,
              const float* __restrict__ W2, const float* __restrict__ W3,
              ushort_t* __restrict__ xb, ushort_t* __restrict__ wb)
{
    const int id = blockIdx.x;
    const float* src;
    ushort_t* dst;
    int i;
    if (id < 8192) {                       // x: NTOK*DIMD/8 = 2M chunks
        i   = id * 256 + threadIdx.x;
        src = x;
        dst = xb;
    } else {                               // weights: 512 blocks per matrix
        const int wid = id - 8192;
        const int m   = wid >> 9;
        i   = (wid & 511) * 256 + threadIdx.x;
        src = (m == 0) ? W0 : (m == 1) ? W1 : (m == 2) ? W2 : W3;
        dst = wb + (size_t)m * DIMD * DIMD;
    }
    const float4* s4 = (const float4*)src;
    const float4 a = s4[i * 2];
    const float4 b = s4[i * 2 + 1];
    u16x8 o;
    o[0] = f2b(a.x); o[1] = f2b(a.y); o[2] = f2b(a.z); o[3] = f2b(a.w);
    o[4] = f2b(b.x); o[5] = f2b(b.y); o[6] = f2b(b.z); o[7] = f2b(b.w);
    *(u16x8*)(dst + (size_t)i * 8) = o;
}

// ---------------------------------------------------------------------------
// Combined projection launch. Blocks 0..511: fused k,v GEMM (256x128, kv
// product + per-chunk decay-weighted sums). Blocks 512..767: r projection
// (256x256 template GEMM with sigmoid epilogue). Both: 512 threads, 128 KB
// LDS, 4-phase counted-vmcnt pipeline, XOR swizzle (global-src + read,
// involution). One launch replaces two -> one fewer sync gap, and the rs
// tail packs behind the kv rounds.
// ---------------------------------------------------------------------------
__global__ __launch_bounds__(512, 2)
void gemm_kvrs(const ushort_t* __restrict__ A,
               const ushort_t* __restrict__ Wk,
               const ushort_t* __restrict__ Wv,
               const ushort_t* __restrict__ Wr,
               const float* __restrict__ td,
               ushort_t* __restrict__ Okv,
               ushort_t* __restrict__ Or,
               float* __restrict__ cs)
{
    __shared__ __align__(16) ushort_t smem[65536];   // 128 KB, carved per path

    const int tid  = threadIdx.x;
    const int lane = tid & 63;
    const int wv   = tid >> 6;        // 0..7
    const int lrow = lane & 15;
    const int kq   = lane >> 4;
    const int s8   = lrow & 7;
    const int sw0  = (kq ^ s8) * 8;        // swizzled elem offset, ksub=0
    const int sw1  = ((kq + 4) ^ s8) * 8;  // swizzled elem offset, ksub=1

    // Staging geometry: dest chunk (row, q) <- global (row, q ^ (row&7)).
    const int r_  = tid >> 3;                       // 0..63
    const int q_  = ((tid & 7) ^ (r_ & 7)) * 8;

    if (blockIdx.x < 512) {
        // ================= kv path: block 256 rows x 128 cols ==============
        ushort_t* As0 = smem;                 // 16384 elts each
        ushort_t* As1 = smem + 16384;
        ushort_t* Bk0 = smem + 32768;         // 8192 elts each
        ushort_t* Bk1 = smem + 40960;
        ushort_t* Bv0 = smem + 49152;
        ushort_t* Bv1 = smem + 57344;

        const int wr   = wv >> 1;     // 0..3 : 64-row chunk (= seq chunk)
        const int wc   = wv & 1;      // 0..1 : 64-col half
        const int row0 = (blockIdx.x & 63) * 256;
        const int e0   = (blockIdx.x >> 6) * 128;

        const size_t aoffs = (size_t)(row0 + r_) * DIMD + q_;
        const size_t boffs = (size_t)(e0 + r_) * DIMD + q_;

#define KV_STAGE_A(dst, k0) do { \
    _Pragma("unroll") \
    for (int it_ = 0; it_ < 4; ++it_) \
        GLL(A + aoffs + (size_t)it_ * 64 * DIMD + (k0), \
            (char*)(dst) + (tid + it_ * 512) * 16); \
} while (0)

#define KV_STAGE_B(Wp, dst, k0) do { \
    _Pragma("unroll") \
    for (int it_ = 0; it_ < 2; ++it_) \
        GLL((Wp) + boffs + (size_t)it_ * 64 * DIMD + (k0), \
            (char*)(dst) + (tid + it_ * 512) * 16); \
} while (0)

        f32x4 ak[4][4], av[4][4];
#pragma unroll
        for (int i = 0; i < 4; i++)
#pragma unroll
            for (int j = 0; j < 4; j++) {
                ak[i][j] = f32x4{0.f, 0.f, 0.f, 0.f};
                av[i][j] = f32x4{0.f, 0.f, 0.f, 0.f};
            }

        // Prologue: A0, B0, A1 in flight; drain A0+B0, keep A1 (vmcnt(4)).
        KV_STAGE_A(As0, 0);
        KV_STAGE_B(Wk, Bk0, 0);
        KV_STAGE_B(Wv, Bv0, 0);
        asm volatile("" ::: "memory");
        KV_STAGE_A(As1, KBK);
        asm volatile("s_waitcnt vmcnt(4)" ::: "memory");
        __builtin_amdgcn_s_barrier();

        auto tile = [&](int kt, ushort_t* Asb, ushort_t* Bkb, ushort_t* Bvb,
                        ushort_t* Bkn, ushort_t* Bvn) {
            bf16x8 af0[4], af1[4], b0[4], b1[4], c0[4], c1[4];

            // ---- P0: read A + Bk (ksub0); issue Bk(kt+1); 16 MFMA k-ksub0
#pragma unroll
            for (int i = 0; i < 4; i++)
                af0[i] = *(const bf16x8*)(Asb + (wr * 64 + i * 16 + lrow) * KBK + sw0);
#pragma unroll
            for (int j = 0; j < 4; j++)
                b0[j] = *(const bf16x8*)(Bkb + (wc * 64 + j * 16 + lrow) * KBK + sw0);
            if (kt + 1 < NKT) KV_STAGE_B(Wk, Bkn, (kt + 1) * KBK);
            __builtin_amdgcn_s_barrier();
            asm volatile("s_waitcnt lgkmcnt(0)" ::: "memory");
            __builtin_amdgcn_sched_barrier(0);
            __builtin_amdgcn_s_setprio(1);
#pragma unroll
            for (int i = 0; i < 4; i++)
#pragma unroll
                for (int j = 0; j < 4; j++)
                    ak[i][j] = __builtin_amdgcn_mfma_f32_16x16x32_bf16(af0[i], b0[j], ak[i][j], 0, 0, 0);
            __builtin_amdgcn_s_setprio(0);
            __builtin_amdgcn_s_barrier();

            // ---- P1: read Bv (ksub0); issue Bv(kt+1); 16 MFMA v-ksub0
#pragma unroll
            for (int j = 0; j < 4; j++)
                c0[j] = *(const bf16x8*)(Bvb + (wc * 64 + j * 16 + lrow) * KBK + sw0);
            if (kt + 1 < NKT) KV_STAGE_B(Wv, Bvn, (kt + 1) * KBK);
            __builtin_amdgcn_s_barrier();
            asm volatile("s_waitcnt lgkmcnt(0)" ::: "memory");
            __builtin_amdgcn_sched_barrier(0);
            __builtin_amdgcn_s_setprio(1);
#pragma unroll
            for (int i = 0; i < 4; i++)
#pragma unroll
                for (int j = 0; j < 4; j++)
                    av[i][j] = __builtin_amdgcn_mfma_f32_16x16x32_bf16(af0[i], c0[j], av[i][j], 0, 0, 0);
            __builtin_amdgcn_s_setprio(0);
            __builtin_amdgcn_s_barrier();

            // ---- P2: read A + Bk (ksub1); 16 MFMA k-ksub1
#pragma unroll
            for (int i = 0; i < 4; i++)
                af1[i] = *(const bf16x8*)(Asb + (wr * 64 + i * 16 + lrow) * KBK + sw1);
#pragma unroll
            for (int j = 0; j < 4; j++)
                b1[j] = *(const bf16x8*)(Bkb + (wc * 64 + j * 16 + lrow) * KBK + sw1);
            __builtin_amdgcn_s_barrier();
            asm volatile("s_waitcnt lgkmcnt(0)" ::: "memory");
            __builtin_amdgcn_sched_barrier(0);
            __builtin_amdgcn_s_setprio(1);
#pragma unroll
            for (int i = 0; i < 4; i++)
#pragma unroll
                for (int j = 0; j < 4; j++)
                    ak[i][j] = __builtin_amdgcn_mfma_f32_16x16x32_bf16(af1[i], b1[j], ak[i][j], 0, 0, 0);
            __builtin_amdgcn_s_setprio(0);
            __builtin_amdgcn_s_barrier();

            // ---- P3: read Bv (ksub1); issue A(kt+2) into vacated A buffer
#pragma unroll
            for (int j = 0; j < 4; j++)
                c1[j] = *(const bf16x8*)(Bvb + (wc * 64 + j * 16 + lrow) * KBK + sw1);
            if (kt + 2 < NKT) KV_STAGE_A(Asb, (kt + 2) * KBK);
            __builtin_amdgcn_s_barrier();
            asm volatile("s_waitcnt lgkmcnt(0)" ::: "memory");
            __builtin_amdgcn_sched_barrier(0);
            __builtin_amdgcn_s_setprio(1);
#pragma unroll
            for (int i = 0; i < 4; i++)
#pragma unroll
                for (int j = 0; j < 4; j++)
                    av[i][j] = __builtin_amdgcn_mfma_f32_16x16x32_bf16(af1[i], c1[j], av[i][j], 0, 0, 0);
            __builtin_amdgcn_s_setprio(0);
            // Drain A(kt+1)+B(kt+1); keep A(kt+2) (newest 4) in flight.
            if (kt < NKT - 2)       asm volatile("s_waitcnt vmcnt(4)" ::: "memory");
            else if (kt == NKT - 2) asm volatile("s_waitcnt vmcnt(0)" ::: "memory");
            __builtin_amdgcn_s_barrier();
        };

        for (int m = 0; m < NKT / 2; ++m) {
            tile(2 * m,     As0, Bk0, Bv0, Bk1, Bv1);
            tile(2 * m + 1, As1, Bk1, Bv1, Bk0, Bv0);
        }

        // Epilogue 1: kv store. C/D layout: col = lane&15, row = quad*4+reg.
#pragma unroll
        for (int i = 0; i < 4; i++)
#pragma unroll
            for (int j = 0; j < 4; j++)
#pragma unroll
                for (int r = 0; r < 4; r++) {
                    const int row = row0 + wr * 64 + i * 16 + kq * 4 + r;
                    const int col = e0 + wc * 64 + j * 16 + lrow;
                    Okv[(size_t)row * DIMD + col] = f2b(ak[i][j][r] * av[i][j][r]);
                }

        // Epilogue 2: per-chunk weighted sum s(d) = sum_row decay^(63-row)kv.
#pragma unroll
        for (int j = 0; j < 4; j++) {
            const int col = e0 + wc * 64 + j * 16 + lrow;
            const float w = -__expf(td[col]);
            float s = 0.f;
#pragma unroll
            for (int i = 0; i < 4; i++)
#pragma unroll
                for (int r = 0; r < 4; r++) {
                    const int rl = i * 16 + kq * 4 + r;           // 0..63
                    s += __expf(w * (float)(63 - rl)) * ak[i][j][r] * av[i][j][r];
                }
            s += __shfl_xor(s, 16);
            s += __shfl_xor(s, 32);
            if (kq == 0) {
                const int gchunk = (row0 >> 6) + wr;              // global chunk
                cs[(size_t)gchunk * DIMD + col] = s;
            }
        }
#undef KV_STAGE_A
#undef KV_STAGE_B
    } else {
        // ================= rs path: 256x256 template + sigmoid =============
        ushort_t* As0 = smem;                 // 16384 elts each
        ushort_t* As1 = smem + 16384;
        ushort_t* Bs0 = smem + 32768;
        ushort_t* Bs1 = smem + 49152;

        const int id2  = blockIdx.x - 512;
        const int wr   = wv >> 2;     // 0..1 : 128-row half
        const int wc   = wv & 3;      // 0..3 : 64-col quarter
        const int row0 = (id2 & 63) * 256;
        const int e0   = (id2 >> 6) * 256;

        const size_t aoffs = (size_t)(row0 + r_) * DIMD + q_;
        const size_t boffs = (size_t)(e0 + r_) * DIMD + q_;

#define RS_STAGE_A(dst, k0) do { \
    _Pragma("unroll") \
    for (int it_ = 0; it_ < 4; ++it_) \
        GLL(A + aoffs + (size_t)it_ * 64 * DIMD + (k0), \
            (char*)(dst) + (tid + it_ * 512) * 16); \
} while (0)

#define RS_STAGE_B(dst, k0) do { \
    _Pragma("unroll") \
    for (int it_ = 0; it_ < 4; ++it_) \
        GLL(Wr + boffs + (size_t)it_ * 64 * DIMD + (k0), \
            (char*)(dst) + (tid + it_ * 512) * 16); \
} while (0)

        f32x4 acc[8][4];
#pragma unroll
        for (int i = 0; i < 8; i++)
#pragma unroll
            for (int j = 0; j < 4; j++)
                acc[i][j] = f32x4{0.f, 0.f, 0.f, 0.f};

        RS_STAGE_A(As0, 0);
        RS_STAGE_B(Bs0, 0);
        asm volatile("" ::: "memory");
        RS_STAGE_A(As1, KBK);
        asm volatile("s_waitcnt vmcnt(4)" ::: "memory");
        __builtin_amdgcn_s_barrier();

        auto tile = [&](int kt, ushort_t* Asb, ushort_t* Bsb, ushort_t* Bsn) {
            bf16x8 af0[8], af1[8], bf0[4], bf1[4];

            // ---- P0
#pragma unroll
            for (int i = 0; i < 8; i++)
                af0[i] = *(const bf16x8*)(Asb + (wr * 128 + i * 16 + lrow) * KBK + sw0);
#pragma unroll
            for (int j = 0; j < 2; j++)
                bf0[j] = *(const bf16x8*)(Bsb + (wc * 64 + j * 16 + lrow) * KBK + sw0);
            if (kt + 1 < NKT) RS_STAGE_B(Bsn, (kt + 1) * KBK);
            __builtin_amdgcn_s_barrier();
            asm volatile("s_waitcnt lgkmcnt(0)" ::: "memory");
            __builtin_amdgcn_sched_barrier(0);
            __builtin_amdgcn_s_setprio(1);
#pragma unroll
            for (int i = 0; i < 8; i++)
#pragma unroll
                for (int j = 0; j < 2; j++)
                    acc[i][j] = __builtin_amdgcn_mfma_f32_16x16x32_bf16(af0[i], bf0[j], acc[i][j], 0, 0, 0);
            __builtin_amdgcn_s_setprio(0);
            __builtin_amdgcn_s_barrier();

            // ---- P1
#pragma unroll
            for (int j = 2; j < 4; j++)
                bf0[j] = *(const bf16x8*)(Bsb + (wc * 64 + j * 16 + lrow) * KBK + sw0);
            __builtin_amdgcn_s_barrier();
            asm volatile("s_waitcnt lgkmcnt(0)" ::: "memory");
            __builtin_amdgcn_sched_barrier(0);
            __builtin_amdgcn_s_setprio(1);
#pragma unroll
            for (int i = 0; i < 8; i++)
#pragma unroll
                for (int j = 2; j < 4; j++)
                    acc[i][j] = __builtin_amdgcn_mfma_f32_16x16x32_bf16(af0[i], bf0[j], acc[i][j], 0, 0, 0);
            __builtin_amdgcn_s_setprio(0);
            __builtin_amdgcn_s_barrier();

            // ---- P2
#pragma unroll
            for (int i = 0; i < 8; i++)
                af1[i] = *(const bf16x8*)(Asb + (wr * 128 + i * 16 + lrow) * KBK + sw1);
#pragma unroll
            for (int j = 0; j < 2; j++)
                bf1[j] = *(const bf16x8*)(Bsb + (wc * 64 + j * 16 + lrow) * KBK + sw1);
            __builtin_amdgcn_s_barrier();
            asm volatile("s_waitcnt lgkmcnt(0)" ::: "memory");
            __builtin_amdgcn_sched_barrier(0);
            __builtin_amdgcn_s_setprio(1);
#pragma unroll
            for (int i = 0; i < 8; i++)
#pragma unroll
                for (int j = 0; j < 2; j++)
                    acc[i][j] = __builtin_amdgcn_mfma_f32_16x16x32_bf16(af1[i], bf1[j], acc[i][j], 0, 0, 0);
            __builtin_amdgcn_s_setprio(0);
            __builtin_amdgcn_s_barrier();

            // ---- P3
#pragma unroll
            for (int j = 2; j < 4; j++)
                bf1[j] = *(const bf16x8*)(Bsb + (wc * 64 + j * 16 + lrow) * KBK + sw1);
            if (kt + 2 < NKT) RS_STAGE_A(Asb, (kt + 2) * KBK);
            __builtin_amdgcn_s_barrier();
            asm volatile("s_waitcnt lgkmcnt(0)" ::: "memory");
            __builtin_amdgcn_sched_barrier(0);
            __builtin_amdgcn_s_setprio(1);
#pragma unroll
            for (int i = 0; i < 8; i++)
#pragma unroll
                for (int j = 2; j < 4; j++)
                    acc[i][j] = __builtin_amdgcn_mfma_f32_16x16x32_bf16(af1[i], bf1[j], acc[i][j], 0, 0, 0);
            __builtin_amdgcn_s_setprio(0);
            if (kt < NKT - 2)       asm volatile("s_waitcnt vmcnt(4)" ::: "memory");
            else if (kt == NKT - 2) asm volatile("s_waitcnt vmcnt(0)" ::: "memory");
            __builtin_amdgcn_s_barrier();
        };

        for (int m = 0; m < NKT / 2; ++m) {
            tile(2 * m,     As0, Bs0, Bs1);
            tile(2 * m + 1, As1, Bs1, Bs0);
        }

#pragma unroll
        for (int i = 0; i < 8; i++)
#pragma unroll
            for (int j = 0; j < 4; j++)
#pragma unroll
                for (int r = 0; r < 4; r++) {
                    const int row = row0 + wr * 128 + i * 16 + kq * 4 + r;
                    const int col = e0 + wc * 64 + j * 16 + lrow;
                    Or[(size_t)row * DIMD + col] =
                        f2b(1.f / (1.f + __expf(-acc[i][j][r])));
                }
#undef RS_STAGE_A
#undef RS_STAGE_B
    }
}

// ---------------------------------------------------------------------------
// Final GEMM: C[n,e] = sum_d A[n,d] * W[e,d], f32 out.
// 256x256 block, 512 threads, 4-phase counted-vmcnt pipeline + swizzle.
// ---------------------------------------------------------------------------
__global__ __launch_bounds__(512, 2)
void gemm_bt(const ushort_t* __restrict__ A,
             const ushort_t* __restrict__ W,
             float* __restrict__ Of)
{
    __shared__ __align__(16) ushort_t As[2][256 * KBK];  // 2 x 32 KB
    __shared__ __align__(16) ushort_t Bs[2][256 * KBK];  // 2 x 32 KB

    const int tid  = threadIdx.x;
    const int lane = tid & 63;
    const int wv   = tid >> 6;
    const int wr   = wv >> 2;
    const int wc   = wv & 3;
    const int lrow = lane & 15;
    const int kq   = lane >> 4;
    const int s8   = lrow & 7;
    const int sw0  = (kq ^ s8) * 8;
    const int sw1  = ((kq + 4) ^ s8) * 8;

    const int row0 = blockIdx.x * 256;
    const int e0   = blockIdx.y * 256;

    const int r_  = tid >> 3;
    const int q_  = ((tid & 7) ^ (r_ & 7)) * 8;
    const size_t aoffs = (size_t)(row0 + r_) * DIMD + q_;
    const size_t boffs = (size_t)(e0 + r_) * DIMD + q_;

#define BT_STAGE_A(dst, k0) do { \
    _Pragma("unroll") \
    for (int it_ = 0; it_ < 4; ++it_) \
        GLL(A + aoffs + (size_t)it_ * 64 * DIMD + (k0), \
            (char*)(dst) + (tid + it_ * 512) * 16); \
} while (0)

#define BT_STAGE_B(dst, k0) do { \
    _Pragma("unroll") \
    for (int it_ = 0; it_ < 4; ++it_) \
        GLL(W + boffs + (size_t)it_ * 64 * DIMD + (k0), \
            (char*)(dst) + (tid + it_ * 512) * 16); \
} while (0)

    f32x4 acc[8][4];
#pragma unroll
    for (int i = 0; i < 8; i++)
#pragma unroll
        for (int j = 0; j < 4; j++)
            acc[i][j] = f32x4{0.f, 0.f, 0.f, 0.f};

    BT_STAGE_A(&As[0][0], 0);
    BT_STAGE_B(&Bs[0][0], 0);
    asm volatile("" ::: "memory");
    BT_STAGE_A(&As[1][0], KBK);
    asm volatile("s_waitcnt vmcnt(4)" ::: "memory");
    __builtin_amdgcn_s_barrier();

    auto tile = [&](int kt, ushort_t* Asb, ushort_t* Bsb, ushort_t* Bsn) {
        bf16x8 af0[8], af1[8], bf0[4], bf1[4];

        // ---- P0
#pragma unroll
        for (int i = 0; i < 8; i++)
            af0[i] = *(const bf16x8*)(Asb + (wr * 128 + i * 16 + lrow) * KBK + sw0);
#pragma unroll
        for (int j = 0; j < 2; j++)
            bf0[j] = *(const bf16x8*)(Bsb + (wc * 64 + j * 16 + lrow) * KBK + sw0);
        if (kt + 1 < NKT) BT_STAGE_B(Bsn, (kt + 1) * KBK);
        __builtin_amdgcn_s_barrier();
        asm volatile("s_waitcnt lgkmcnt(0)" ::: "memory");
        __builtin_amdgcn_sched_barrier(0);
        __builtin_amdgcn_s_setprio(1);
#pragma unroll
        for (int i = 0; i < 8; i++)
#pragma unroll
            for (int j = 0; j < 2; j++)
                acc[i][j] = __builtin_amdgcn_mfma_f32_16x16x32_bf16(af0[i], bf0[j], acc[i][j], 0, 0, 0);
        __builtin_amdgcn_s_setprio(0);
        __builtin_amdgcn_s_barrier();

        // ---- P1
#pragma unroll
        for (int j = 2; j < 4; j++)
            bf0[j] = *(const bf16x8*)(Bsb + (wc * 64 + j * 16 + lrow) * KBK + sw0);
        __builtin_amdgcn_s_barrier();
        asm volatile("s_waitcnt lgkmcnt(0)" ::: "memory");
        __builtin_amdgcn_sched_barrier(0);
        __builtin_amdgcn_s_setprio(1);
#pragma unroll
        for (int i = 0; i < 8; i++)
#pragma unroll
            for (int j = 2; j < 4; j++)
                acc[i][j] = __builtin_amdgcn_mfma_f32_16x16x32_bf16(af0[i], bf0[j], acc[i][j], 0, 0, 0);
        __builtin_amdgcn_s_setprio(0);
        __builtin_amdgcn_s_barrier();

        // ---- P2
#pragma unroll
        for (int i = 0; i < 8; i++)
            af1[i] = *(const bf16x8*)(Asb + (wr * 128 + i * 16 + lrow) * KBK + sw1);
#pragma unroll
        for (int j = 0; j < 2; j++)
            bf1[j] = *(const bf16x8*)(Bsb + (wc * 64 + j * 16 + lrow) * KBK + sw1);
        __builtin_amdgcn_s_barrier();
        asm volatile("s_waitcnt lgkmcnt(0)" ::: "memory");
        __builtin_amdgcn_sched_barrier(0);
        __builtin_amdgcn_s_setprio(1);
#pragma unroll
        for (int i = 0; i < 8; i++)
#pragma unroll
            for (int j = 0; j < 2; j++)
                acc[i][j] = __builtin_amdgcn_mfma_f32_16x16x32_bf16(af1[i], bf1[j], acc[i][j], 0, 0, 0);
        __builtin_amdgcn_s_setprio(0);
        __builtin_amdgcn_s_barrier();

        // ---- P3
#pragma unroll
        for (int j = 2; j < 4; j++)
            bf1[j] = *(const bf16x8*)(Bsb + (wc * 64 + j * 16 + lrow) * KBK + sw1);
        if (kt + 2 < NKT) BT_STAGE_A(Asb, (kt + 2) * KBK);
        __builtin_amdgcn_s_barrier();
        asm volatile("s_waitcnt lgkmcnt(0)" ::: "memory");
        __builtin_amdgcn_sched_barrier(0);
        __builtin_amdgcn_s_setprio(1);
#pragma unroll
        for (int i = 0; i < 8; i++)
#pragma unroll
            for (int j = 2; j < 4; j++)
                acc[i][j] = __builtin_amdgcn_mfma_f32_16x16x32_bf16(af1[i], bf1[j], acc[i][j], 0, 0, 0);
        __builtin_amdgcn_s_setprio(0);
        if (kt < NKT - 2)       asm volatile("s_waitcnt vmcnt(4)" ::: "memory");
        else if (kt == NKT - 2) asm volatile("s_waitcnt vmcnt(0)" ::: "memory");
        __builtin_amdgcn_s_barrier();
    };

    for (int m = 0; m < NKT / 2; ++m) {
        tile(2 * m,     &As[0][0], &Bs[0][0], &Bs[1][0]);
        tile(2 * m + 1, &As[1][0], &Bs[1][0], &Bs[0][0]);
    }

#pragma unroll
    for (int i = 0; i < 8; i++)
#pragma unroll
        for (int j = 0; j < 4; j++)
#pragma unroll
            for (int r = 0; r < 4; r++) {
                const int row = row0 + wr * 128 + i * 16 + kq * 4 + r;
                const int col = e0 + wc * 64 + j * 16 + lrow;
                Of[(size_t)row * DIMD + col] = acc[i][j][r];
            }
#undef BT_STAGE_A
#undef BT_STAGE_B
}

// ---------------------------------------------------------------------------
// Emit with self-scan: out_pre = r*(st + eu*kv); st = decay*st + kv.
// Incoming chunk state is computed from RAW cs (per-chunk sums) by a short
// prefix loop per thread — replaces the chunk_scan launch. Identical FP op
// order to the old chunk_scan (st = decayL*st + cs[c'] ascending).
// ---------------------------------------------------------------------------
__global__ __launch_bounds__(64)
void emit(const ushort_t* __restrict__ kvb, const ushort_t* __restrict__ rb,
          const float* __restrict__ td, const float* __restrict__ tf,
          const float* __restrict__ cs, ushort_t* __restrict__ op)
{
    const int t  = blockIdx.x * 64 + threadIdx.x;    // 32768 threads
    const int d0 = (t & (DIMD / 8 - 1)) * 8;
    const int bc = t >> 7;
    const int c  = bc & (NCHUNK - 1);
    const int b  = bc >> 6;

    float decay[8], eu[8], dL[8], st[8];
#pragma unroll
    for (int j = 0; j < 8; j++) {
        const float w = -__expf(td[d0 + j]);
        decay[j] = __expf(w);
        dL[j]    = __expf(w * (float)CHUNK);
        eu[j]    = __expf(tf[d0 + j]);
        st[j]    = 0.f;
    }

    // Prefix over raw per-chunk sums: st = incoming state at chunk c.
    const float* csb = cs + ((size_t)b * NCHUNK) * DIMD + d0;
    for (int cp = 0; cp < c; cp++) {
        const float4 s0 = *(const float4*)(csb + (size_t)cp * DIMD);
        const float4 s1 = *(const float4*)(csb + (size_t)cp * DIMD + 4);
        st[0] = dL[0] * st[0] + s0.x; st[1] = dL[1] * st[1] + s0.y;
        st[2] = dL[2] * st[2] + s0.z; st[3] = dL[3] * st[3] + s0.w;
        st[4] = dL[4] * st[4] + s1.x; st[5] = dL[5] * st[5] + s1.y;
        st[6] = dL[6] * st[6] + s1.z; st[7] = dL[7] * st[7] + s1.w;
    }

    size_t off = ((size_t)b * SEQ + (size_t)c * CHUNK) * DIMD + d0;
#pragma unroll 8
    for (int i = 0; i < CHUNK; i++) {
        const u16x8 kv8 = *(const u16x8*)(kvb + off);
        const u16x8 r8  = *(const u16x8*)(rb + off);
        u16x8 o8;
#pragma unroll
        for (int j = 0; j < 8; j++) {
            const float kv = b2f(kv8[j]);
            o8[j] = f2b(b2f(r8[j]) * (st[j] + eu[j] * kv));
            st[j] = decay[j] * st[j] + kv;
        }
        *(u16x8*)(op + off) = o8;
        off += DIMD;
    }
}

// ---------------------------------------------------------------------------
// ws: xb/pbuf 32 MiB + weights 8 MiB + cs 1 MiB = 41 MiB.
// d_out (64 MiB f32) doubles as kvb+rb scratch (dead before final GEMM).
// 4 launches: conv_all -> gemm_kvrs -> emit -> gemm_bt.
// ---------------------------------------------------------------------------
extern "C" void kernel_launch(void* const* d_in, const int* in_sizes, int n_in,
                              void* d_out, int out_size, void* d_ws, size_t ws_size,
                              hipStream_t stream)
{
    const float* x  = (const float*)d_in[0];
    const float* Wk = (const float*)d_in[1];
    const float* Wv = (const float*)d_in[2];
    const float* Wr = (const float*)d_in[3];
    const float* Wo = (const float*)d_in[4];
    const float* td = (const float*)d_in[5];
    const float* tf = (const float*)d_in[6];

    ushort_t* xb  = (ushort_t*)d_ws;                       // 32 MiB; reused as pbuf
    ushort_t* Wb  = xb + (size_t)NTOK * DIMD;              // 8 MiB (4 matrices)
    ushort_t* Wkb = Wb;
    ushort_t* Wvb = Wb + (size_t)DIMD * DIMD;
    ushort_t* Wrb = Wb + 2 * (size_t)DIMD * DIMD;
    ushort_t* Wob = Wb + 3 * (size_t)DIMD * DIMD;
    float*    cs  = (float*)(Wb + 4 * (size_t)DIMD * DIMD); // 1 MiB
    ushort_t* pbuf = xb;

    ushort_t* kvb = (ushort_t*)d_out;                      // 32 MiB scratch
    ushort_t* rb  = kvb + (size_t)NTOK * DIMD;             // 32 MiB scratch
    float*    out = (float*)d_out;

    // 0) all conversions (x + 4 weight matrices) in one launch
    conv_all<<<8192 + 2048, 256, 0, stream>>>(x, Wk, Wv, Wr, Wo, xb, Wb);

    // 1) kv projection (+ per-chunk aggregates) and r projection, one launch
    gemm_kvrs<<<512 + 256, 512, 0, stream>>>(
        xb, Wkb, Wvb, Wrb, td, kvb, rb, cs);

    // 2) emit (self-scans cs) -> pbuf (xb region)
    emit<<<BATCH * NCHUNK * (DIMD / 8) / 64, 64, 0, stream>>>(
        kvb, rb, td, tf, cs, pbuf);

    // 3) out = out_pre @ Wo^T (f32 epilogue, overwrites d_out)
    gemm_bt<<<dim3(NTOK / 256, DIMD / 256), 512, 0, stream>>>(pbuf, Wob, out);
}